// Round 3
// baseline (379.380 us; speedup 1.0000x reference)
//
#include <hip/hip_runtime.h>

// ============================================================================
// DIAGNOSTIC ROUND: wo_kernel runs its QK^T+exp2+LDS pass TWICE (bit-identical,
// idempotent; pass B reads K through an opaque pointer to defeat CSE).
// Purpose: measure the QK-compute component of wo via delta vs R2 baseline
// (353.1 us), and/or force wo into the rocprof top-5 window for full counters.
// Stores / PV / lsum / prep are UNCHANGED from R2. Numerics bit-identical.
// ============================================================================

#define SQ 4096
#define DD 64
#define NB 4
#define NEL (NB*SQ*DD)   // 1,048,576 elements per tensor

typedef __attribute__((ext_vector_type(4))) float f32x4;
typedef __attribute__((ext_vector_type(8))) __bf16 bf16x8;

__device__ __forceinline__ unsigned short f2bf(float f) {
  unsigned int u = __builtin_bit_cast(unsigned int, f);
  u = (u + 0x7FFFu + ((u >> 16) & 1u)) >> 16;   // RNE
  return (unsigned short)u;
}

__device__ __forceinline__ bf16x8 ldfrag(const unsigned short* p) {
  uint4 u = *(const uint4*)p;
  return __builtin_bit_cast(bf16x8, u);
}

// pack 8 f32 -> bf16x8; native casts emit v_cvt_pk_bf16_f32
__device__ __forceinline__ bf16x8 pack_bf8(f32x4 a, f32x4 b) {
  bf16x8 r;
  r[0] = (__bf16)a[0]; r[1] = (__bf16)a[1]; r[2] = (__bf16)a[2]; r[3] = (__bf16)a[3];
  r[4] = (__bf16)b[0]; r[5] = (__bf16)b[1]; r[6] = (__bf16)b[2]; r[7] = (__bf16)b[3];
  return r;
}

// ---------------- prep: Q,K -> bf16 ; V -> bf16 transposed [D][S] ----------------
__global__ __launch_bounds__(256) void prep_kernel(
    const float* __restrict__ q, const float* __restrict__ k,
    const float* __restrict__ v, unsigned short* __restrict__ ws)
{
  unsigned short* qbf = ws;
  unsigned short* kbf = ws + (size_t)NEL;
  unsigned short* vt  = ws + 2*(size_t)NEL;
  const int bid = blockIdx.x;
  const int tid = threadIdx.x;
  if (bid < 1024) {
    const float* src = (bid < 512) ? q : k;
    unsigned short* dst = (bid < 512) ? qbf : kbf;
    const int base = (bid & 511) * 512 + tid;
#pragma unroll
    for (int i = 0; i < 2; ++i) {
      int idx = base + i * 256;
      float4 f = ((const float4*)src)[idx];
      ushort4 o;
      o.x = f2bf(f.x); o.y = f2bf(f.y); o.z = f2bf(f.z); o.w = f2bf(f.w);
      ((ushort4*)dst)[idx] = o;
    }
  } else {
    // transpose V: one block per (batch, 64-row s-tile)
    __shared__ unsigned short tile[64][66];
    const int t  = bid - 1024;
    const int bb = t >> 6;
    const int st = t & 63;
    const float* vb = v + (size_t)bb * SQ * DD + (size_t)st * 64 * DD;
    const int r  = tid >> 4;
    const int c4 = tid & 15;
#pragma unroll
    for (int j = 0; j < 4; ++j) {
      int row = r + j * 16;
      float4 f = ((const float4*)(vb + (size_t)row * DD))[c4];
      tile[row][c4 * 4 + 0] = f2bf(f.x);
      tile[row][c4 * 4 + 1] = f2bf(f.y);
      tile[row][c4 * 4 + 2] = f2bf(f.z);
      tile[row][c4 * 4 + 3] = f2bf(f.w);
    }
    __syncthreads();
    unsigned short* vtb = vt + (size_t)bb * DD * SQ;
#pragma unroll
    for (int j = 0; j < 4; ++j) {
      int d   = r + j * 16;
      int s0l = c4 * 4;
      ushort4 o;
      o.x = tile[s0l + 0][d];
      o.y = tile[s0l + 1][d];
      o.z = tile[s0l + 2][d];
      o.w = tile[s0l + 3][d];
      ((ushort4*)(vtb + (size_t)d * SQ + st * 64))[c4] = o;
    }
  }
}

// ---------------- kernel 1: softmax denominators -> li2 = -log2(sum) ----------------
__global__ __launch_bounds__(512, 6) void lsum_kernel(
    const unsigned short* __restrict__ qbf,
    const unsigned short* __restrict__ kbf,
    float* __restrict__ li2_g)
{
  __shared__ float lred[8][4][4];
  const int tid  = threadIdx.x;
  const int wave = tid >> 6;
  const int lane = tid & 63;
  const int l16  = lane & 15;
  const int quad = lane >> 4;

  const int bidx = blockIdx.x;
  const int b    = bidx & 3;          // XCD x sees only batch x&3
  const int qt   = 255 - (bidx >> 2); // heavy first

  const unsigned short* Qb = qbf + (size_t)b * SQ * DD;
  const unsigned short* Kb = kbf + (size_t)b * SQ * DD;
  const int q0    = qt * 16;
  const int rowg0 = q0 + quad * 4;

  bf16x8 aQ0, aQ1;
  {
    const unsigned short* qrow = Qb + (size_t)(q0 + l16) * DD + quad * 8;
    aQ0 = ldfrag(qrow);
    aQ1 = ldfrag(qrow + 32);
  }

  const int nkt = (qt >> 2) + 1;
  const float SC = 0.125f * 1.4426950408889634f;
  const f32x4 zf = {0.f, 0.f, 0.f, 0.f};

  float lsum[4] = {0.f, 0.f, 0.f, 0.f};
  for (int kt = wave; kt < nkt; kt += 8) {
    const int k0 = kt * 64;
    f32x4 acc[4] = {zf, zf, zf, zf};
#pragma unroll
    for (int ct = 0; ct < 4; ++ct) {
      const unsigned short* krow = Kb + (size_t)(k0 + ct * 16 + l16) * DD + quad * 8;
      bf16x8 b0 = ldfrag(krow);
      bf16x8 b1 = ldfrag(krow + 32);
      acc[ct] = __builtin_amdgcn_mfma_f32_16x16x32_bf16(aQ0, b0, acc[ct], 0, 0, 0);
      acc[ct] = __builtin_amdgcn_mfma_f32_16x16x32_bf16(aQ1, b1, acc[ct], 0, 0, 0);
    }
#pragma unroll
    for (int ct = 0; ct < 4; ++ct) {
      const int colg = k0 + ct * 16 + l16;
#pragma unroll
      for (int r = 0; r < 4; ++r) {
        float tt = (colg <= rowg0 + r) ? acc[ct][r] * SC : -1e30f;
        lsum[r] += __builtin_amdgcn_exp2f(tt);
      }
    }
  }
#pragma unroll
  for (int r = 0; r < 4; ++r) {
    float v = lsum[r];
    v += __shfl_xor(v, 1);
    v += __shfl_xor(v, 2);
    v += __shfl_xor(v, 4);
    v += __shfl_xor(v, 8);
    lsum[r] = v;
  }
  if (l16 == 0) {
#pragma unroll
    for (int r = 0; r < 4; ++r) lred[wave][quad][r] = lsum[r];
  }
  __syncthreads();
  if (tid < 16) {
    float s = 0.f;
#pragma unroll
    for (int w = 0; w < 8; ++w) s += lred[w][tid >> 2][tid & 3];
    li2_g[(size_t)b * SQ + q0 + tid] = -__builtin_amdgcn_logf(s);  // -log2(sum)
  }
}

// ---------------- kernel 2 (PROBE): QK pass doubled, rest unchanged ----------------
__global__ __launch_bounds__(512, 4) void wo_kernel(
    const unsigned short* __restrict__ qbf,
    const unsigned short* __restrict__ kbf,
    const unsigned short* __restrict__ vtp,
    const float* __restrict__ li2_g,
    float* __restrict__ out_vec,
    float* __restrict__ out_w)
{
  __shared__ __align__(16) float pt[8][16][132];

  const int tid  = threadIdx.x;
  const int wave = tid >> 6;
  const int lane = tid & 63;
  const int l16  = lane & 15;
  const int quad = lane >> 4;
  const int half = lane >> 5;       // 0 | 1
  const int c32  = lane & 31;

  const int bidx = blockIdx.x;
  const int b    = bidx & 3;
  const int qt   = 255 - (bidx >> 2);

  const unsigned short* Qb = qbf + (size_t)b * SQ * DD;
  const unsigned short* Kb = kbf + (size_t)b * SQ * DD;
  const unsigned short* Vt = vtp + (size_t)b * DD * SQ;  // [D][S]
  float* Wb = out_w  + (size_t)b * SQ * SQ;
  float* Ob = out_vec + (size_t)b * SQ * DD;

  const int q0    = qt * 16;
  const int rowg0 = q0 + quad * 4;

  bf16x8 aQ0, aQ1;
  {
    const unsigned short* qrow = Qb + (size_t)(q0 + l16) * DD + quad * 8;
    aQ0 = ldfrag(qrow);
    aQ1 = ldfrag(qrow + 32);
  }

  // opaque alias of Kb: compiler cannot prove pass B == pass A -> no CSE.
  const unsigned short* Kb_op = Kb;
  asm volatile("" : "+v"(Kb_op));

  float li2[4];
#pragma unroll
  for (int r = 0; r < 4; ++r)
    li2[r] = li2_g[(size_t)b * SQ + rowg0 + r];   // broadcast load

  const int nkt = (qt >> 2) + 1;
  const int nst = (nkt + 1) >> 1;                 // 128-col strips
  const float SC = 0.125f * 1.4426950408889634f;
  const f32x4 zf = {0.f, 0.f, 0.f, 0.f};
  f32x4 accO[4] = {zf, zf, zf, zf};

  for (int st = wave; st < nst; st += 8) {
    const int k0c = st * 128;
    // ---- pass A + pass B (probe): identical QK^T + exp2 into LDS ----
#pragma unroll
    for (int pass = 0; pass < 2; ++pass) {
      const unsigned short* Kp = pass ? Kb_op : Kb;
#pragma unroll
      for (int h = 0; h < 2; ++h) {
        const int k0 = k0c + h * 64;
        f32x4 acc[4] = {zf, zf, zf, zf};
#pragma unroll
        for (int ct = 0; ct < 4; ++ct) {
          const unsigned short* krow = Kp + (size_t)(k0 + ct * 16 + l16) * DD + quad * 8;
          bf16x8 b0 = ldfrag(krow);
          bf16x8 b1 = ldfrag(krow + 32);
          acc[ct] = __builtin_amdgcn_mfma_f32_16x16x32_bf16(aQ0, b0, acc[ct], 0, 0, 0);
          acc[ct] = __builtin_amdgcn_mfma_f32_16x16x32_bf16(aQ1, b1, acc[ct], 0, 0, 0);
        }
#pragma unroll
        for (int ct = 0; ct < 4; ++ct) {
          const int colg = k0 + ct * 16 + l16;
#pragma unroll
          for (int r = 0; r < 4; ++r) {
            float tt = (colg <= rowg0 + r) ? __builtin_fmaf(acc[ct][r], SC, li2[r])
                                           : -1e30f;
            pt[wave][quad * 4 + r][h * 64 + ct * 16 + l16] = __builtin_amdgcn_exp2f(tt);
          }
        }
      }
    }
    // ---- W store: inst i covers rows {2i, 2i+1} x 512B contiguous ----
#pragma unroll
    for (int i = 0; i < 8; ++i) {
      const int rr = 2 * i + half;
      f32x4 pv = *(const f32x4*)&pt[wave][rr][c32 * 4];
      *(f32x4*)(Wb + (size_t)(q0 + rr) * SQ + k0c + c32 * 4) = pv;
    }
    // ---- PV over 4 K-chunks of 32 ----
#pragma unroll
    for (int kk = 0; kk < 4; ++kk) {
      const float* pr = &pt[wave][l16][kk * 32 + quad * 8];
      f32x4 p0 = *(const f32x4*)pr;
      f32x4 p1 = *(const f32x4*)(pr + 4);
      bf16x8 aP = pack_bf8(p0, p1);
#pragma unroll
      for (int ct = 0; ct < 4; ++ct) {
        const unsigned short* vrow =
            Vt + (size_t)(ct * 16 + l16) * SQ + k0c + kk * 32 + quad * 8;
        bf16x8 bv = ldfrag(vrow);
        accO[ct] = __builtin_amdgcn_mfma_f32_16x16x32_bf16(aP, bv, accO[ct], 0, 0, 0);
      }
    }
  }

  // ---- combine partial O across 8 waves (alias each wave's pt region) ----
  float* ow_mine = &pt[wave][0][0];
#pragma unroll
  for (int ct = 0; ct < 4; ++ct)
#pragma unroll
    for (int r = 0; r < 4; ++r)
      ow_mine[(quad * 4 + r) * 64 + ct * 16 + l16] = accO[ct][r];
  __syncthreads();
#pragma unroll
  for (int i = 0; i < 2; ++i) {
    int idx = tid + i * 512;
    int row = idx >> 6, col = idx & 63;
    float s = 0.f;
#pragma unroll
    for (int w = 0; w < 8; ++w) s += pt[w][0][row * 64 + col];
    Ob[(size_t)(q0 + row) * DD + col] = s;
  }

  // ---- zero-fill fully-masked columns [nst*128, S) for the 16 rows ----
  const int zc0 = nst * 128;
  const int nz4 = (SQ - zc0) >> 2;
  if (nz4 > 0) {
    const f32x4 z = {0.f, 0.f, 0.f, 0.f};
    for (int r = 0; r < 16; ++r) {
      f32x4* zp = (f32x4*)(Wb + (size_t)(q0 + r) * SQ + zc0);
      for (int i = tid; i < nz4; i += 512)
        zp[i] = z;
    }
  }
}

extern "C" void kernel_launch(void* const* d_in, const int* in_sizes, int n_in,
                              void* d_out, int out_size, void* d_ws, size_t ws_size,
                              hipStream_t stream) {
  const float* q = (const float*)d_in[0];
  const float* k = (const float*)d_in[1];
  const float* v = (const float*)d_in[2];
  float* out_vec = (float*)d_out;
  float* out_w   = out_vec + (size_t)NB * SQ * DD;
  unsigned short* ws = (unsigned short*)d_ws;      // 3*NEL*2 = 6 MB bf16 tensors
  float* li2_g = (float*)(ws + 3 * (size_t)NEL);   // +64 KB row normalizers

  hipLaunchKernelGGL(prep_kernel, dim3(1280), dim3(256), 0, stream, q, k, v, ws);
  hipLaunchKernelGGL(lsum_kernel, dim3(1024), dim3(512), 0, stream,
                     ws, ws + (size_t)NEL, li2_g);
  hipLaunchKernelGGL(wo_kernel, dim3(1024), dim3(512), 0, stream,
                     ws, ws + (size_t)NEL, ws + 2 * (size_t)NEL,
                     li2_g, out_vec, out_w);
}

// Round 4
// 348.385 us; speedup vs baseline: 1.0890x; 1.0890x over previous
//
#include <hip/hip_runtime.h>

// ============================================================================
// R4: block-cooperative W stores. All 8 waves build one shared 16x1024 P-tile
// in LDS, then stores are partitioned BY ROW: each wave writes 2 rows x 4KB
// contiguous (vs R2: per-wave 512B segments scattered over 16 rows). Targets
// HBM write locality — the last live theory for wo's ~90us store-path excess
// (QK pass measured at 26us by the R3 duplication probe; occupancy and
// per-instruction store shape falsified R1/R2).
// ============================================================================

#define SQ 4096
#define DD 64
#define NB 4
#define NEL (NB*SQ*DD)   // 1,048,576 elements per tensor

typedef __attribute__((ext_vector_type(4))) float f32x4;
typedef __attribute__((ext_vector_type(8))) __bf16 bf16x8;

__device__ __forceinline__ unsigned short f2bf(float f) {
  unsigned int u = __builtin_bit_cast(unsigned int, f);
  u = (u + 0x7FFFu + ((u >> 16) & 1u)) >> 16;   // RNE
  return (unsigned short)u;
}

__device__ __forceinline__ bf16x8 ldfrag(const unsigned short* p) {
  uint4 u = *(const uint4*)p;
  return __builtin_bit_cast(bf16x8, u);
}

// pack 8 f32 -> bf16x8; native casts emit v_cvt_pk_bf16_f32
__device__ __forceinline__ bf16x8 pack_bf8(f32x4 a, f32x4 b) {
  bf16x8 r;
  r[0] = (__bf16)a[0]; r[1] = (__bf16)a[1]; r[2] = (__bf16)a[2]; r[3] = (__bf16)a[3];
  r[4] = (__bf16)b[0]; r[5] = (__bf16)b[1]; r[6] = (__bf16)b[2]; r[7] = (__bf16)b[3];
  return r;
}

// ---------------- prep: Q,K -> bf16 ; V -> bf16 transposed [D][S] ----------------
__global__ __launch_bounds__(256) void prep_kernel(
    const float* __restrict__ q, const float* __restrict__ k,
    const float* __restrict__ v, unsigned short* __restrict__ ws)
{
  unsigned short* qbf = ws;
  unsigned short* kbf = ws + (size_t)NEL;
  unsigned short* vt  = ws + 2*(size_t)NEL;
  const int bid = blockIdx.x;
  const int tid = threadIdx.x;
  if (bid < 1024) {
    const float* src = (bid < 512) ? q : k;
    unsigned short* dst = (bid < 512) ? qbf : kbf;
    const int base = (bid & 511) * 512 + tid;
#pragma unroll
    for (int i = 0; i < 2; ++i) {
      int idx = base + i * 256;
      float4 f = ((const float4*)src)[idx];
      ushort4 o;
      o.x = f2bf(f.x); o.y = f2bf(f.y); o.z = f2bf(f.z); o.w = f2bf(f.w);
      ((ushort4*)dst)[idx] = o;
    }
  } else {
    // transpose V: one block per (batch, 64-row s-tile)
    __shared__ unsigned short tile[64][66];
    const int t  = bid - 1024;
    const int bb = t >> 6;
    const int st = t & 63;
    const float* vb = v + (size_t)bb * SQ * DD + (size_t)st * 64 * DD;
    const int r  = tid >> 4;
    const int c4 = tid & 15;
#pragma unroll
    for (int j = 0; j < 4; ++j) {
      int row = r + j * 16;
      float4 f = ((const float4*)(vb + (size_t)row * DD))[c4];
      tile[row][c4 * 4 + 0] = f2bf(f.x);
      tile[row][c4 * 4 + 1] = f2bf(f.y);
      tile[row][c4 * 4 + 2] = f2bf(f.z);
      tile[row][c4 * 4 + 3] = f2bf(f.w);
    }
    __syncthreads();
    unsigned short* vtb = vt + (size_t)bb * DD * SQ;
#pragma unroll
    for (int j = 0; j < 4; ++j) {
      int d   = r + j * 16;
      int s0l = c4 * 4;
      ushort4 o;
      o.x = tile[s0l + 0][d];
      o.y = tile[s0l + 1][d];
      o.z = tile[s0l + 2][d];
      o.w = tile[s0l + 3][d];
      ((ushort4*)(vtb + (size_t)d * SQ + st * 64))[c4] = o;
    }
  }
}

// ---------------- kernel 1: softmax denominators -> li2 = -log2(sum) ----------------
__global__ __launch_bounds__(512, 6) void lsum_kernel(
    const unsigned short* __restrict__ qbf,
    const unsigned short* __restrict__ kbf,
    float* __restrict__ li2_g)
{
  __shared__ float lred[8][4][4];
  const int tid  = threadIdx.x;
  const int wave = tid >> 6;
  const int lane = tid & 63;
  const int l16  = lane & 15;
  const int quad = lane >> 4;

  const int bidx = blockIdx.x;
  const int b    = bidx & 3;          // XCD x sees only batch x&3
  const int qt   = 255 - (bidx >> 2); // heavy first

  const unsigned short* Qb = qbf + (size_t)b * SQ * DD;
  const unsigned short* Kb = kbf + (size_t)b * SQ * DD;
  const int q0    = qt * 16;
  const int rowg0 = q0 + quad * 4;

  bf16x8 aQ0, aQ1;
  {
    const unsigned short* qrow = Qb + (size_t)(q0 + l16) * DD + quad * 8;
    aQ0 = ldfrag(qrow);
    aQ1 = ldfrag(qrow + 32);
  }

  const int nkt = (qt >> 2) + 1;
  const float SC = 0.125f * 1.4426950408889634f;
  const f32x4 zf = {0.f, 0.f, 0.f, 0.f};

  float lsum[4] = {0.f, 0.f, 0.f, 0.f};
  for (int kt = wave; kt < nkt; kt += 8) {
    const int k0 = kt * 64;
    f32x4 acc[4] = {zf, zf, zf, zf};
#pragma unroll
    for (int ct = 0; ct < 4; ++ct) {
      const unsigned short* krow = Kb + (size_t)(k0 + ct * 16 + l16) * DD + quad * 8;
      bf16x8 b0 = ldfrag(krow);
      bf16x8 b1 = ldfrag(krow + 32);
      acc[ct] = __builtin_amdgcn_mfma_f32_16x16x32_bf16(aQ0, b0, acc[ct], 0, 0, 0);
      acc[ct] = __builtin_amdgcn_mfma_f32_16x16x32_bf16(aQ1, b1, acc[ct], 0, 0, 0);
    }
#pragma unroll
    for (int ct = 0; ct < 4; ++ct) {
      const int colg = k0 + ct * 16 + l16;
#pragma unroll
      for (int r = 0; r < 4; ++r) {
        float tt = (colg <= rowg0 + r) ? acc[ct][r] * SC : -1e30f;
        lsum[r] += __builtin_amdgcn_exp2f(tt);
      }
    }
  }
#pragma unroll
  for (int r = 0; r < 4; ++r) {
    float v = lsum[r];
    v += __shfl_xor(v, 1);
    v += __shfl_xor(v, 2);
    v += __shfl_xor(v, 4);
    v += __shfl_xor(v, 8);
    lsum[r] = v;
  }
  if (l16 == 0) {
#pragma unroll
    for (int r = 0; r < 4; ++r) lred[wave][quad][r] = lsum[r];
  }
  __syncthreads();
  if (tid < 16) {
    float s = 0.f;
#pragma unroll
    for (int w = 0; w < 8; ++w) s += lred[w][tid >> 2][tid & 3];
    li2_g[(size_t)b * SQ + q0 + tid] = -__builtin_amdgcn_logf(s);  // -log2(sum)
  }
}

// ---------------- kernel 2: cooperative strips; row-contiguous W stores ----------------
// Per strip: 8 waves fill one 16x1024 f32 P-tile (each wave a 128-col window),
// sync, then wave w stores rows {2w, 2w+1} as 4KB contiguous runs; PV consumes
// each wave's own window. Row length 1044 (=20 mod 32): quad row-stride 4*1044
// = 16 mod 32 -> 2-way (free) banking on P writes.
__global__ __launch_bounds__(512, 4) void wo_kernel(
    const unsigned short* __restrict__ qbf,
    const unsigned short* __restrict__ kbf,
    const unsigned short* __restrict__ vtp,
    const float* __restrict__ li2_g,
    float* __restrict__ out_vec,
    float* __restrict__ out_w)
{
  __shared__ __align__(16) float ptS[16][1044];   // 66,816 B; aliased for O-combine

  const int tid  = threadIdx.x;
  const int wv   = tid >> 6;
  const int lane = tid & 63;
  const int l16  = lane & 15;
  const int quad = lane >> 4;

  const int bidx = blockIdx.x;
  const int b    = bidx & 3;
  const int qt   = 255 - (bidx >> 2);

  const unsigned short* Qb = qbf + (size_t)b * SQ * DD;
  const unsigned short* Kb = kbf + (size_t)b * SQ * DD;
  const unsigned short* Vt = vtp + (size_t)b * DD * SQ;  // [D][S]
  float* Wb = out_w  + (size_t)b * SQ * SQ;
  float* Ob = out_vec + (size_t)b * SQ * DD;

  const int q0    = qt * 16;
  const int rowg0 = q0 + quad * 4;

  bf16x8 aQ0, aQ1;
  {
    const unsigned short* qrow = Qb + (size_t)(q0 + l16) * DD + quad * 8;
    aQ0 = ldfrag(qrow);
    aQ1 = ldfrag(qrow + 32);
  }

  float li2[4];
#pragma unroll
  for (int r = 0; r < 4; ++r)
    li2[r] = li2_g[(size_t)b * SQ + rowg0 + r];   // broadcast load

  const int nkt  = (qt >> 2) + 1;
  const int ncov = nkt * 64;                      // causal-covered columns
  const int nstb = (nkt + 15) >> 4;               // 1024-col strips
  const float SC = 0.125f * 1.4426950408889634f;
  const f32x4 zf = {0.f, 0.f, 0.f, 0.f};
  f32x4 accO[4] = {zf, zf, zf, zf};

  const int wc0 = wv * 128;                       // wave's window inside strip

  for (int s = 0; s < nstb; ++s) {
    const int k0s  = s << 10;
    const int c0   = k0s + wc0;                   // wave window's global col
    const bool live = (c0 <= q0 + 15);            // any unmasked element?

    if (live) {
      // ---- QK^T + exp2 into shared tile, two 64-col halves ----
#pragma unroll
      for (int h = 0; h < 2; ++h) {
        const int k0 = c0 + h * 64;
        f32x4 acc[4] = {zf, zf, zf, zf};
#pragma unroll
        for (int ct = 0; ct < 4; ++ct) {
          const unsigned short* krow = Kb + (size_t)(k0 + ct * 16 + l16) * DD + quad * 8;
          bf16x8 b0 = ldfrag(krow);
          bf16x8 b1 = ldfrag(krow + 32);
          acc[ct] = __builtin_amdgcn_mfma_f32_16x16x32_bf16(aQ0, b0, acc[ct], 0, 0, 0);
          acc[ct] = __builtin_amdgcn_mfma_f32_16x16x32_bf16(aQ1, b1, acc[ct], 0, 0, 0);
        }
        // normalized P directly: exp2(score*SC + li2) == exp2(score*SC)/sum
#pragma unroll
        for (int ct = 0; ct < 4; ++ct) {
          const int colg = k0 + ct * 16 + l16;
#pragma unroll
          for (int r = 0; r < 4; ++r) {
            float tt = (colg <= rowg0 + r) ? __builtin_fmaf(acc[ct][r], SC, li2[r])
                                           : -1e30f;
            ptS[quad * 4 + r][wc0 + h * 64 + ct * 16 + l16] =
                __builtin_amdgcn_exp2f(tt);
          }
        }
      }
    } else {
      // fully-masked window: zero the LDS window (still stored with the strip)
#pragma unroll
      for (int i = 0; i < 8; ++i) {
        int idx = i * 64 + lane;        // 0..511 over 16 rows x 32 f32x4
        int row = idx >> 5;
        int c4  = idx & 31;
        *(f32x4*)&ptS[row][wc0 + c4 * 4] = zf;
      }
    }
    __syncthreads();

    // ---- W store: wave w -> rows {2w, 2w+1}, 4 x 1KB-contiguous insts/row ----
#pragma unroll
    for (int rr = 0; rr < 2; ++rr) {
      const int row = 2 * wv + rr;
      float* wrow = Wb + (size_t)(q0 + row) * SQ + k0s;
#pragma unroll
      for (int i = 0; i < 4; ++i) {
        f32x4 pv = *(const f32x4*)&ptS[row][i * 256 + lane * 4];
        *(f32x4*)(wrow + i * 256 + lane * 4) = pv;
      }
    }

    // ---- PV over this wave's window (skip if all-masked: P==0) ----
    if (live) {
#pragma unroll
      for (int kk = 0; kk < 4; ++kk) {
        const float* pr = &ptS[l16][wc0 + kk * 32 + quad * 8];
        f32x4 p0 = *(const f32x4*)pr;
        f32x4 p1 = *(const f32x4*)(pr + 4);
        bf16x8 aP = pack_bf8(p0, p1);
#pragma unroll
        for (int ct = 0; ct < 4; ++ct) {
          const unsigned short* vrow =
              Vt + (size_t)(ct * 16 + l16) * SQ + c0 + kk * 32 + quad * 8;
          bf16x8 bv = ldfrag(vrow);
          accO[ct] = __builtin_amdgcn_mfma_f32_16x16x32_bf16(aP, bv, accO[ct], 0, 0, 0);
        }
      }
    }
    __syncthreads();   // tile free for next strip's writes
  }

  // ---- combine partial O across 8 waves (flat alias, stride 2088 words) ----
  float* base = &ptS[0][0];
  float* ow_mine = base + wv * 2088;
#pragma unroll
  for (int ct = 0; ct < 4; ++ct)
#pragma unroll
    for (int r = 0; r < 4; ++r)
      ow_mine[(quad * 4 + r) * 64 + ct * 16 + l16] = accO[ct][r];
  __syncthreads();
#pragma unroll
  for (int i = 0; i < 2; ++i) {
    int idx = tid + i * 512;
    int row = idx >> 6, col = idx & 63;
    float s = 0.f;
#pragma unroll
    for (int w = 0; w < 8; ++w) s += base[w * 2088 + row * 64 + col];
    Ob[(size_t)(q0 + row) * DD + col] = s;
  }

  // ---- zero-fill fully-masked columns [nstb*1024, S) for the 16 rows ----
  const int zc0 = nstb << 10;
  const int nz4 = (SQ - zc0) >> 2;
  if (nz4 > 0) {
    for (int r = 0; r < 16; ++r) {
      f32x4* zp = (f32x4*)(Wb + (size_t)(q0 + r) * SQ + zc0);
      for (int i = tid; i < nz4; i += 512)
        zp[i] = zf;
    }
  }
}

extern "C" void kernel_launch(void* const* d_in, const int* in_sizes, int n_in,
                              void* d_out, int out_size, void* d_ws, size_t ws_size,
                              hipStream_t stream) {
  const float* q = (const float*)d_in[0];
  const float* k = (const float*)d_in[1];
  const float* v = (const float*)d_in[2];
  float* out_vec = (float*)d_out;
  float* out_w   = out_vec + (size_t)NB * SQ * DD;
  unsigned short* ws = (unsigned short*)d_ws;      // 3*NEL*2 = 6 MB bf16 tensors
  float* li2_g = (float*)(ws + 3 * (size_t)NEL);   // +64 KB row normalizers

  hipLaunchKernelGGL(prep_kernel, dim3(1280), dim3(256), 0, stream, q, k, v, ws);
  hipLaunchKernelGGL(lsum_kernel, dim3(1024), dim3(512), 0, stream,
                     ws, ws + (size_t)NEL, li2_g);
  hipLaunchKernelGGL(wo_kernel, dim3(1024), dim3(512), 0, stream,
                     ws, ws + (size_t)NEL, ws + 2 * (size_t)NEL,
                     li2_g, out_vec, out_w);
}